// Round 10
// baseline (100.920 us; speedup 1.0000x reference)
//
#include <hip/hip_runtime.h>
#include <math.h>

#define NPTS 16384
#define DIM  16
#define KH   32                 // K=18 padded to 32 (fp16; rounding ~1e-3 final err vs 3.8e-2 threshold)
#define CSPLIT 32
#define COLS_PER_BLOCK (NPTS / CSPLIT)        // 512
#define JT_TOTAL (COLS_PER_BLOCK / 16)        // 32
#define ROWS_PER_BLOCK 512
#define RBLK (NPTS / ROWS_PER_BLOCK)          // 32
#define MT 8                                   // 16-row M-tiles per wave (128 rows/wave)
#define NBLOCKS (RBLK * CSPLIT)                // 1024 — one pass, each pair computed once

typedef _Float16 f16x8 __attribute__((ext_vector_type(8)));
typedef float    f32x4 __attribute__((ext_vector_type(4)));

// ---------------------------------------------------------------------------
// prep: asymmetric K=18 packing folding ALL norm terms into the dot so ONE
// MFMA accumulator serves both row- and col-min:
//   A-form (set1): [rx*x, rx*cx, rx, 0...]      cx = ||x||^2/2
//   B-form (set2): [ry*y, -ry, -ry*cy, 0...]    cy = ||y||^2/2
//   dot = -0.5*rx*ry*||x-y||^2  (<= 0; arcosh monotone => max acc = nearest)
// FRAGMENT-PACKED: point p -> g=p/16, c=p%16; half-offset g*512+quad*128+c*8
// (= g*512 + lane*8) so pairs reads linear b128, 0 bank conflicts.
// Zeroes the output scalar (d_out re-poisoned 0xAA before every launch).
// ---------------------------------------------------------------------------
__global__ __launch_bounds__(256) void prep_kernel(const float* __restrict__ s1,
                                                   const float* __restrict__ s2,
                                                   _Float16* __restrict__ Xa,
                                                   _Float16* __restrict__ Yb,
                                                   float* __restrict__ out) {
    int b = blockIdx.x, tid = threadIdx.x;
    if (b == 0 && tid == 0) out[0] = 0.f;

    int isX = (b < 64);
    const float* src = isX ? s1 : s2;
    _Float16* dst = isX ? Xa : Yb;
    int p = (isX ? b : b - 64) * 256 + tid;

    const float4* s4 = (const float4*)(src + (size_t)p * DIM);
    float4 A = s4[0], B = s4[1], C = s4[2], D = s4[3];
    float v[DIM] = {A.x,A.y,A.z,A.w, B.x,B.y,B.z,B.w,
                    C.x,C.y,C.z,C.w, D.x,D.y,D.z,D.w};
    float n2 = 0.f;
#pragma unroll
    for (int k = 0; k < DIM; ++k) n2 = fmaf(v[k], v[k], n2);
    float r = 1.0f / (1.0f - n2);           // norms < 0.7 -> safe

    __attribute__((aligned(16))) _Float16 buf[KH];
#pragma unroll
    for (int k = 0; k < DIM; ++k) buf[k] = (_Float16)(r * v[k]);
    if (isX) { buf[16] = (_Float16)(0.5f * r * n2);  buf[17] = (_Float16)r; }
    else     { buf[16] = (_Float16)(-r);             buf[17] = (_Float16)(-0.5f * r * n2); }
#pragma unroll
    for (int k = 18; k < KH; ++k) buf[k] = (_Float16)0.f;

    int g = p >> 4, c = p & 15;
    const uint4* b4 = (const uint4*)buf;
#pragma unroll
    for (int q = 0; q < 4; ++q) {
        size_t off = (size_t)g * 512 + (size_t)q * 128 + (size_t)c * 8;
        *(uint4*)(dst + off) = b4[q];
    }
}

// ---------------------------------------------------------------------------
// pairs (ONE pass, NO global atomics, NO fences): 1024 blocks (32 row-blocks
// x 32 col-splits), 40 KB LDS => 4 blocks/CU. Wave holds 128 set1-rows in
// registers (8 b128 loads); 32 KB set2-stripe staged once via global_load_lds
// w=16, one barrier. Per 16-col tile: 1 ds_read_b128 + 8 MFMA + 32 row fmax
// + ~32 col fmax + 2 shuffles + 1 plain colWave write. Winners leave the
// block as PLAIN COALESCED float stores to Rpart[cs][row] / Cpart[r][col]
// (r5-r9's ~1M global atomicMin RMWs were the hidden ~25us serialization —
// this round's change). Kernel-boundary coherence makes the partials visible
// to finalize (proven r1-r3).
// HARD LESSONS ENCODED:
//  - r4/r8: NO __threadfence / agent-scope counter in per-block path
//    (device-wide L2 writeback serializes -> 170-180us, all pipes idle).
//  - r4: lb(256,2) only — never cap VGPRs below the ~95-reg live set.
// C/D layout (measured): col = lane&15, row = quad*4 + reg.
// ---------------------------------------------------------------------------
__global__ __launch_bounds__(256, 2) void pairs_kernel(const _Float16* __restrict__ Xa,
                                                       const _Float16* __restrict__ Yb,
                                                       float* __restrict__ Rpart,
                                                       float* __restrict__ Cpart) {
    __shared__ __align__(16) _Float16 Bs[COLS_PER_BLOCK * KH];   // 32 KB
    __shared__ float colWave[4][COLS_PER_BLOCK];                 // 8 KB

    const int b = blockIdx.x;
    const int r  = b >> 5;                   // row-block 0..31
    const int cs = b & 31;                   // col-split 0..31

    const int tid = threadIdx.x;
    const int lane = tid & 63, w = tid >> 6;
    const int c = lane & 15, quad = lane >> 4;

    // ---- stage the 32 KB set2-stripe: 8 direct-to-LDS DMAs per thread
    {
        const char* gsrc = (const char*)Yb + (size_t)cs * (COLS_PER_BLOCK * KH * 2)
                         + (size_t)tid * 16;
        char* lb = (char*)Bs + (size_t)tid * 16;
#pragma unroll
        for (int e = 0; e < 8; ++e) {
            __builtin_amdgcn_global_load_lds(
                (const __attribute__((address_space(1))) unsigned int*)(gsrc + e * 4096),
                (__attribute__((address_space(3))) unsigned int*)(lb + e * 4096),
                16, 0, 0);
        }
    }

    // ---- A fragments: 128 rows/wave resident in registers for the whole sweep
    f16x8 af[MT];
#pragma unroll
    for (int t = 0; t < MT; ++t) {
        int g = r * 32 + w * 8 + t;
        af[t] = *(const f16x8*)&Xa[(size_t)g * 512 + (size_t)lane * 8];
    }

    f32x4 rowmax[MT];
#pragma unroll
    for (int t = 0; t < MT; ++t)
        rowmax[t] = (f32x4){-INFINITY, -INFINITY, -INFINITY, -INFINITY};

    const f32x4 zero = (f32x4){0.f, 0.f, 0.f, 0.f};

    __syncthreads();   // LDS stripe complete

#pragma unroll 2
    for (int jt = 0; jt < JT_TOTAL; ++jt) {
        f16x8 bf = *(const f16x8*)&Bs[jt * 512 + lane * 8];
        float cm = -INFINITY;               // col-max over this wave's 128 rows
#pragma unroll
        for (int t = 0; t < MT; ++t) {
            f32x4 acc = __builtin_amdgcn_mfma_f32_16x16x32_f16(af[t], bf, zero, 0, 0, 0);
            rowmax[t][0] = fmaxf(rowmax[t][0], acc[0]);
            rowmax[t][1] = fmaxf(rowmax[t][1], acc[1]);
            rowmax[t][2] = fmaxf(rowmax[t][2], acc[2]);
            rowmax[t][3] = fmaxf(rowmax[t][3], acc[3]);
            float cv = fmaxf(fmaxf(acc[0], acc[1]), fmaxf(acc[2], acc[3]));
            cm = fmaxf(cm, cv);
        }
        // reduce over the 4 quads (rows) -> per-col max for these 16 cols
        cm = fmaxf(cm, __shfl_xor(cm, 16, 64));
        cm = fmaxf(cm, __shfl_xor(cm, 32, 64));
        if (quad == 0)
            colWave[w][jt * 16 + c] = cm;    // plain write: col owned once per wave
    }

    __syncthreads();   // all waves done reading Bs / writing colWave

    // ---- col winners: cross-wave max, plain coalesced store to Cpart[r][col]
#pragma unroll
    for (int e = 0; e < 2; ++e) {
        int i = tid + e * 256;
        float cm = fmaxf(fmaxf(colWave[0][i], colWave[1][i]),
                         fmaxf(colWave[2][i], colWave[3][i]));
        Cpart[(size_t)r * NPTS + cs * COLS_PER_BLOCK + i] = cm;
    }

    // ---- row winners: shuffle-reduce to c==0 lanes, park in LDS (reuse Bs),
    //      then plain coalesced store to Rpart[cs][row]
    float* rowred = (float*)Bs;             // Bs is dead now (barrier above)
#pragma unroll
    for (int t = 0; t < MT; ++t) {
#pragma unroll
        for (int e = 0; e < 4; ++e) {
            float m = rowmax[t][e];
            m = fmaxf(m, __shfl_xor(m, 1, 64));
            m = fmaxf(m, __shfl_xor(m, 2, 64));
            m = fmaxf(m, __shfl_xor(m, 4, 64));
            m = fmaxf(m, __shfl_xor(m, 8, 64));
            if (c == 0)
                rowred[w * 128 + t * 16 + quad * 4 + e] = m;
        }
    }
    __syncthreads();
#pragma unroll
    for (int e = 0; e < 2; ++e) {
        int i = tid + e * 256;
        Rpart[(size_t)cs * NPTS + r * ROWS_PER_BLOCK + i] = rowred[i];
    }
}

// ---------------------------------------------------------------------------
// finalize: reduce 32 partials per point (4MB, L2-resident), arcosh, mean,
// atomicAdd scalar. Blocks 0..63 rows, 64..127 cols (uniform per block).
// t = -4*maxacc = u-1 >= 0 (clamped: fp16 noise guard);
// arcosh(1+t) = log1p(t + sqrt(t*(t+2)))
// ---------------------------------------------------------------------------
__global__ __launch_bounds__(256) void finalize_kernel(const float* __restrict__ Rpart,
                                                       const float* __restrict__ Cpart,
                                                       float* __restrict__ out) {
    int idx = blockIdx.x * 256 + threadIdx.x;
    const bool isRow = (idx < NPTS);
    const float* P = isRow ? Rpart : Cpart;
    int i = isRow ? idx : idx - NPTS;
    float m = P[i];
#pragma unroll 4
    for (int s = 1; s < CSPLIT; ++s) m = fmaxf(m, P[(size_t)s * NPTS + i]);
    float t = fmaxf(-4.0f * m, 0.0f);
    float d = log1pf(t + sqrtf(t * (t + 2.0f)));
    float val = d * (1.0f / NPTS);

    __shared__ float sred[256];
    sred[threadIdx.x] = val;
    __syncthreads();
    for (int s = 128; s > 0; s >>= 1) {
        if (threadIdx.x < s) sred[threadIdx.x] += sred[threadIdx.x + s];
        __syncthreads();
    }
    if (threadIdx.x == 0) atomicAdd(out, sred[0]);
}

// ---------------------------------------------------------------------------
extern "C" void kernel_launch(void* const* d_in, const int* in_sizes, int n_in,
                              void* d_out, int out_size, void* d_ws, size_t ws_size,
                              hipStream_t stream) {
    const float* set1 = (const float*)d_in[0];
    const float* set2 = (const float*)d_in[1];
    float* out = (float*)d_out;

    // ws: Xa 1MB + Yb 1MB (fp16 fragment-packed) + Rpart 2MB + Cpart 2MB
    _Float16* Xa = (_Float16*)d_ws;
    _Float16* Yb = Xa + (size_t)NPTS * KH;
    float* Rpart = (float*)(Yb + (size_t)NPTS * KH);
    float* Cpart = Rpart + (size_t)CSPLIT * NPTS;

    prep_kernel<<<128, 256, 0, stream>>>(set1, set2, Xa, Yb, out);
    pairs_kernel<<<NBLOCKS, 256, 0, stream>>>(Xa, Yb, Rpart, Cpart);
    finalize_kernel<<<2 * NPTS / 256, 256, 0, stream>>>(Rpart, Cpart, out);
}

// Round 11
// 92.290 us; speedup vs baseline: 1.0935x; 1.0935x over previous
//
#include <hip/hip_runtime.h>
#include <math.h>

#define NPTS 16384
#define DIM  16
#define KH   32                 // fp16 direct: [a18, 0*14]; fp16 rounding ~1e-3 final err vs 3.8e-2 threshold
#define CSPLIT 16
#define COLS_PER_BLOCK (NPTS / CSPLIT)        // 1024
#define JT_TOTAL (COLS_PER_BLOCK / 16)        // 64
#define ROWS_PER_BLOCK 512
#define RBLK (NPTS / ROWS_PER_BLOCK)          // 32
#define MT 8                                   // 16-row M-tiles per wave (128 rows/wave)
#define NBLOCKS (2 * RBLK * CSPLIT)            // 1024

typedef _Float16 f16x8 __attribute__((ext_vector_type(8)));
typedef float    f32x4 __attribute__((ext_vector_type(4)));

// ---------------------------------------------------------------------------
// BEST-MEASURED VARIANT (round 6, 92.8 us total) — reverted to as final.
// Session findings encoded:
//  - totals r5-r10 = {95.0, 92.8, 93.9, 96.7, 100.9} while MFMA work fell 4x
//    and occupancy doubled: total is harness-dominated (42us ws-poison fill
//    at 82% HBM peak + ~35us replay overhead), kernels ~15us.
//  - r4/r8: NEVER put __threadfence / agent-scope counters in the per-block
//    path (device-wide L2 writeback serialization, +140us, all pipes idle).
//  - r4: lb(256,2) only — capping VGPRs below the ~95-reg live set demotes
//    af[]/rowmax[] to memory (2.8x regression).
//  - fragment-packed global layout => linear b128 LDS reads, 0 bank conflicts.
// ---------------------------------------------------------------------------
// prep: augmented vectors with <x',y'> = -0.5*rx*ry*||x-y||^2, cast to fp16.
//   x' = rx*[x, -||x||^2/2, 1]   y' = ry*[y, 1, -||y||^2/2]   (K padded to 32)
// FRAGMENT-PACKED: point p -> group g=p/16, c=p%16; half-offset
//   g*512 + quad*128 + c*8  (== g*512 + lane*8) holds k = quad*8+j.
// Also inits the atomicMin array and zeroes the output scalar.
// ---------------------------------------------------------------------------
__global__ __launch_bounds__(256) void prep_kernel(const float* __restrict__ s1,
                                                   const float* __restrict__ s2,
                                                   _Float16* __restrict__ Xp,
                                                   _Float16* __restrict__ Yp,
                                                   unsigned int* __restrict__ rowfinal,
                                                   float* __restrict__ out) {
    int b = blockIdx.x, tid = threadIdx.x;
    int idx = b * 256 + tid;                // 0..32767
    rowfinal[idx] = 0xFFFFFFFFu;            // uint-min identity
    if (idx == 0) out[0] = 0.f;

    int isX = (b < 64);
    const float* src = isX ? s1 : s2;
    _Float16* dst = isX ? Xp : Yp;
    int p = (isX ? b : b - 64) * 256 + tid;

    const float4* s4 = (const float4*)(src + (size_t)p * DIM);
    float4 A = s4[0], B = s4[1], C = s4[2], D = s4[3];
    float v[DIM] = {A.x,A.y,A.z,A.w, B.x,B.y,B.z,B.w,
                    C.x,C.y,C.z,C.w, D.x,D.y,D.z,D.w};
    float n2 = 0.f;
#pragma unroll
    for (int k = 0; k < DIM; ++k) n2 = fmaf(v[k], v[k], n2);
    float r = 1.0f / (1.0f - n2);           // norms < 0.7 -> safe
    float a[18];
#pragma unroll
    for (int k = 0; k < DIM; ++k) a[k] = r * v[k];
    if (isX) { a[16] = -0.5f * r * n2; a[17] = r; }
    else     { a[16] = r;              a[17] = -0.5f * r * n2; }

    __attribute__((aligned(16))) _Float16 buf[KH];
#pragma unroll
    for (int k = 0; k < 18; ++k) buf[k] = (_Float16)a[k];
#pragma unroll
    for (int k = 18; k < KH; ++k) buf[k] = (_Float16)0.f;

    int g = p >> 4, c = p & 15;
    const uint4* b4 = (const uint4*)buf;
#pragma unroll
    for (int q = 0; q < 4; ++q) {
        size_t off = (size_t)g * 512 + (size_t)q * 128 + (size_t)c * 8;
        *(uint4*)(dst + off) = b4[q];
    }
}

// ---------------------------------------------------------------------------
// pairs: 1024 blocks (2 passes x 32 row-blocks x 16 col-splits), 2 blocks/CU
// (64 KB LDS each). Wave holds 128 rows of A in registers (8 b128 global
// loads). The ENTIRE 1024-col B-stripe (64 KB) is staged to LDS once via
// global_load_lds w=16, ONE __syncthreads, then 64 jt iterations of pure
// ds_read_b128 + 8 independent MFMA + 32 fmax with no further barriers.
// arcosh monotone => running max of raw accumulators; cross-lane reduce once
// per block -> atomicMin uint (acc<=0: float-max == uint-min).
// Pass 0: rows=set1 (term1); pass 1: rows=set2 (term2).
// C/D layout (measured): col = lane&15, row = quad*4 + reg.
// ---------------------------------------------------------------------------
__global__ __launch_bounds__(256, 2) void pairs_kernel(const _Float16* __restrict__ Xp,
                                                       const _Float16* __restrict__ Yp,
                                                       unsigned int* __restrict__ rowfinal) {
    __shared__ __align__(16) _Float16 Bs[COLS_PER_BLOCK * KH];   // 64 KB

    const int b = blockIdx.x;
    const int pass = b >> 9;                 // 512 blocks per pass
    const int within = b & 511;
    const int r  = within >> 4;              // row-block 0..31
    const int cs = within & 15;              // col-split 0..15

    const _Float16* Aset = pass ? Yp : Xp;
    const _Float16* Bset = pass ? Xp : Yp;
    unsigned int* outMin = rowfinal + pass * NPTS;

    const int tid = threadIdx.x;
    const int lane = tid & 63, w = tid >> 6;
    const int c = lane & 15, quad = lane >> 4;

    // ---- stage the whole 64 KB B-stripe: 16 direct-to-LDS DMAs per thread
    {
        const char* gsrc = (const char*)Bset + (size_t)cs * (COLS_PER_BLOCK * KH * 2)
                         + (size_t)tid * 16;
        char* lb = (char*)Bs + (size_t)tid * 16;
#pragma unroll
        for (int e = 0; e < 16; ++e) {
            __builtin_amdgcn_global_load_lds(
                (const __attribute__((address_space(1))) unsigned int*)(gsrc + e * 4096),
                (__attribute__((address_space(3))) unsigned int*)(lb + e * 4096),
                16, 0, 0);
        }
    }

    // ---- A fragments: 128 rows/wave resident in registers for the whole sweep
    f16x8 af[MT];
#pragma unroll
    for (int t = 0; t < MT; ++t) {
        int g = r * 32 + w * 8 + t;
        af[t] = *(const f16x8*)&Aset[(size_t)g * 512 + (size_t)lane * 8];
    }

    f32x4 rowmax[MT];
#pragma unroll
    for (int t = 0; t < MT; ++t)
        rowmax[t] = (f32x4){-INFINITY, -INFINITY, -INFINITY, -INFINITY};

    const f32x4 zero = (f32x4){0.f, 0.f, 0.f, 0.f};

    __syncthreads();   // single barrier: LDS stripe complete

#pragma unroll 4
    for (int jt = 0; jt < JT_TOTAL; ++jt) {
        f16x8 bf = *(const f16x8*)&Bs[jt * 512 + lane * 8];
#pragma unroll
        for (int t = 0; t < MT; ++t) {
            f32x4 acc = __builtin_amdgcn_mfma_f32_16x16x32_f16(af[t], bf, zero, 0, 0, 0);
            rowmax[t][0] = fmaxf(rowmax[t][0], acc[0]);
            rowmax[t][1] = fmaxf(rowmax[t][1], acc[1]);
            rowmax[t][2] = fmaxf(rowmax[t][2], acc[2]);
            rowmax[t][3] = fmaxf(rowmax[t][3], acc[3]);
        }
    }

    // ---- once-per-block: reduce over 16 c-lanes, atomicMin into rowfinal
#pragma unroll
    for (int t = 0; t < MT; ++t) {
#pragma unroll
        for (int e = 0; e < 4; ++e) {
            float m = rowmax[t][e];
            m = fmaxf(m, __shfl_xor(m, 1, 64));
            m = fmaxf(m, __shfl_xor(m, 2, 64));
            m = fmaxf(m, __shfl_xor(m, 4, 64));
            m = fmaxf(m, __shfl_xor(m, 8, 64));
            if (c == 0) {
                int row = ((r * 32 + w * 8 + t) << 4) + quad * 4 + e;
                atomicMin(&outMin[row], __float_as_uint(m));
            }
        }
    }
}

// ---------------------------------------------------------------------------
// finalize: 32768 winners -> arcosh -> mean -> atomicAdd scalar.
// t = -4*maxacc = u-1 >= 0 (clamped: fp16 noise can push acc slightly > 0);
// arcosh(1+t) = log1p(t + sqrt(t*(t+2)))
// ---------------------------------------------------------------------------
__global__ __launch_bounds__(256) void finalize_kernel(const unsigned int* __restrict__ rowfinal,
                                                       float* __restrict__ out) {
    int idx = blockIdx.x * 256 + threadIdx.x;
    float f = __uint_as_float(rowfinal[idx]);     // max accumulator
    float t = fmaxf(-4.0f * f, 0.0f);
    float d = log1pf(t + sqrtf(t * (t + 2.0f)));
    float val = d * (1.0f / NPTS);

    __shared__ float sred[256];
    sred[threadIdx.x] = val;
    __syncthreads();
    for (int s = 128; s > 0; s >>= 1) {
        if (threadIdx.x < s) sred[threadIdx.x] += sred[threadIdx.x + s];
        __syncthreads();
    }
    if (threadIdx.x == 0) atomicAdd(out, sred[0]);
}

// ---------------------------------------------------------------------------
extern "C" void kernel_launch(void* const* d_in, const int* in_sizes, int n_in,
                              void* d_out, int out_size, void* d_ws, size_t ws_size,
                              hipStream_t stream) {
    const float* set1 = (const float*)d_in[0];
    const float* set2 = (const float*)d_in[1];
    float* out = (float*)d_out;

    // ws: Xp 1MB + Yp 1MB (fp16 fragment-packed) + rowfinal 128KB
    _Float16* Xp = (_Float16*)d_ws;
    _Float16* Yp = Xp + (size_t)NPTS * KH;
    unsigned int* rowfinal = (unsigned int*)(Yp + (size_t)NPTS * KH);

    prep_kernel<<<128, 256, 0, stream>>>(set1, set2, Xp, Yp, rowfinal, out);
    pairs_kernel<<<NBLOCKS, 256, 0, stream>>>(Xp, Yp, rowfinal);
    finalize_kernel<<<2 * NPTS / 256, 256, 0, stream>>>(rowfinal, out);
}